// Round 6
// baseline (304.645 us; speedup 1.0000x reference)
//
#include <hip/hip_runtime.h>

typedef __bf16 bf16x8 __attribute__((ext_vector_type(8)));
typedef float floatx4 __attribute__((ext_vector_type(4)));

__device__ __forceinline__ unsigned int cvtpk_bf16(float lo, float hi) {
    unsigned int r;
    asm("v_cvt_pk_bf16_f32 %0, %1, %2" : "=v"(r) : "v"(lo), "v"(hi));
    return r;   // [bf16(lo), bf16(hi)] packed, hardware RNE
}

__device__ __forceinline__ void async_copy16(const void* g, void* l) {
    __builtin_amdgcn_global_load_lds(
        (const __attribute__((address_space(1))) unsigned int*)g,
        (__attribute__((address_space(3))) unsigned int*)l,
        16, 0, 0);
}

__device__ __forceinline__ float sigmoidf_fast(float x) {
    return 1.f / (1.f + __expf(-x));
}
__device__ __forceinline__ float tanhf_fast(float x) {
    return 1.f - 2.f / (__expf(2.f * x) + 1.f);   // exact at +-inf
}

// Prep: [x|h] -> Abf [8192,2048] bf16 (identity rows) and [Wx|Wh] -> Wbf
// [4096,2048] bf16 with row permutation
//   out row n' = hg*64 + gate*16 + hl  <-  src row gate*1024 + hg*16 + hl
// (h = hg*16 + hl). 16 elems/thread; conversion via hardware
// v_cvt_pk_bf16_f32 (software RNE was ~5 VALU ops/elem -> prep was
// VALU-bound at ~1.1 TB/s; hw cvt_pk makes it memory-bound).
__global__ __launch_bounds__(256) void prep_cat(
        const float* __restrict__ x, const float* __restrict__ h,
        const float* __restrict__ Wx, const float* __restrict__ Wh,
        unsigned short* __restrict__ Abf, unsigned short* __restrict__ Wbf) {
    int T = blockIdx.x * 256 + threadIdx.x;
    size_t e;
    const float* a;
    const float* b;
    unsigned short* o;
    size_t srow;
    if (T < 1048576) {                       // A: 16,777,216 elems / 16
        e = (size_t)T * 16;
        a = x; b = h; o = Abf;
        srow = e >> 11;
    } else {                                 // W: 8,388,608 elems / 16
        e = (size_t)(T - 1048576) * 16;
        a = Wx; b = Wh; o = Wbf;
        int m = (int)(e >> 11);              // permuted (output) row
        int hg = m >> 6, gate = (m >> 4) & 3, hl = m & 15;
        srow = (size_t)(gate * 1024 + hg * 16 + hl);
    }
    int k = (int)(e & 2047);                 // 16-aligned; never straddles x|h
    const float* src = (k < 1024) ? (a + srow * 1024 + k)
                                  : (b + srow * 1024 + (k - 1024));
    float4 v0 = ((const float4*)src)[0];
    float4 v1 = ((const float4*)src)[1];
    float4 v2 = ((const float4*)src)[2];
    float4 v3 = ((const float4*)src)[3];
    uint4 p0, p1;
    p0.x = cvtpk_bf16(v0.x, v0.y);  p0.y = cvtpk_bf16(v0.z, v0.w);
    p0.z = cvtpk_bf16(v1.x, v1.y);  p0.w = cvtpk_bf16(v1.z, v1.w);
    p1.x = cvtpk_bf16(v2.x, v2.y);  p1.y = cvtpk_bf16(v2.z, v2.w);
    p1.z = cvtpk_bf16(v3.x, v3.y);  p1.w = cvtpk_bf16(v3.z, v3.w);
    ((uint4*)(o + e))[0] = p0;
    ((uint4*)(o + e))[1] = p1;
}

// Fused GEMM + LSTM, 256x256 tile, BK=64, 8 waves (2M x 4N), 16x16x32 MFMA,
// 4 phases/K-tile.  Prefetch: A one K-tile ahead (phases 1-2 -> nxt.A),
// B TWO K-tiles ahead (phases 3-4 -> cur.B, legal because all B reads of
// cur happen in phases 1-2).  Boundary wait vmcnt(4): youngest 4 in-flight
// loads are B(t+2)'s, so A(t+1) AND B(t+1) are guaranteed landed -- counted,
// never drained to 0 mid-loop (m218: drain0 forfeits the pipeline).
// LDS swizzle both-sides: phys_chunk = logical ^ (row&7) ^ ((row>>2)&4).
// Epilogue register-only (gate-per-16-row W permutation).
#define NT 32   // K / 64

__global__ __launch_bounds__(512) void gemm_lstm(
        const unsigned short* __restrict__ A,     // [8192,2048] bf16
        const unsigned short* __restrict__ W,     // [4096,2048] bf16, gate-per-16 rows
        const float* __restrict__ bx, const float* __restrict__ bh,
        const float* __restrict__ c1,             // [8192,1024] f32
        float* __restrict__ out) {                // h_new [8192,1024] then c
    __shared__ __align__(16) char smem[131072];

    const int tid = threadIdx.x;
    const int lane = tid & 63;
    const int wave = tid >> 6;
    const int wm = wave >> 2;        // 0..1 -> M half (128 rows)
    const int wn = wave & 3;         // 0..3 -> 64-col span (1 h-group x 4 gates)
    const int l15 = lane & 15;
    const int quad = lane >> 4;      // 0..3
    const int L7 = l15 & 7;

    // XCD swizzle, 8x8 tile chunk per XCD.
    int bid = (int)blockIdx.x;
    int x8 = bid & 7;
    int q = bid >> 3;                 // 0..63
    const int tileM = (((x8 >> 1) * 8) + (q & 7)) * 256;
    const int tileN = (((x8 & 1) * 8) + (q >> 3)) * 256;

    auto stage = [&](const unsigned short* __restrict__ G, int grow0, int kt,
                     char* ldsbase) {
#pragma unroll
        for (int r = 0; r < 2; ++r) {
            int rh = r * 64 + (tid >> 3);
            int kc = (tid & 7) ^ (rh & 7) ^ ((rh >> 2) & 4);
            const unsigned short* src = G + (size_t)(grow0 + rh) * 2048 + kt + kc * 8;
            async_copy16(src, ldsbase + r * 8192 + wave * 1024);
        }
    };

    char* b0 = smem;
    char* b1 = smem + 65536;

    // Prologue: A(0), B(0) -> b0; B(1) -> b1.B (stays in flight, vmcnt(4)).
    stage(A, tileM,        0, b0);
    stage(A, tileM + 128,  0, b0 + 16384);
    stage(W, tileN,        0, b0 + 32768);
    stage(W, tileN + 128,  0, b0 + 49152);
    stage(W, tileN,       64, b1 + 32768);
    stage(W, tileN + 128, 64, b1 + 49152);
    asm volatile("s_waitcnt vmcnt(4)" ::: "memory");
    __builtin_amdgcn_s_barrier();
    __builtin_amdgcn_sched_barrier(0);

    // Per-lane read offsets: frag at row-base r0 (mult of 16, parity p):
    // phys chunk = (ks*4+quad) ^ (l15&7) ^ (p*4); co folds in l15*128.
    int co[2][2];
#pragma unroll
    for (int p = 0; p < 2; ++p)
#pragma unroll
        for (int ks = 0; ks < 2; ++ks)
            co[p][ks] = l15 * 128 + ((((ks * 4 + quad) ^ L7 ^ (p * 4))) << 4);

    floatx4 acc[8][4] = {};
    bf16x8 fA[4][2];   // qm=0 A frags
    bf16x8 fD[4][2];   // qm=1 A frags
    bf16x8 fB[2][2];   // qn=0 B frags (gates 0,1)
    bf16x8 fC[2][2];   // qn=1 B frags (gates 2,3)

    for (int t = 0; t < NT; ++t) {
        char* cur = smem + (t & 1) * 65536;
        char* nxt = smem + ((t + 1) & 1) * 65536;
        const char* Ab = cur + wm * 16384;              // wave's A half (128 rows)
        const char* Bb = cur + 32768 + wn * 8192;       // wave's B span (64 rows)

        // ---------- phase 1: quadrant (qm0, qn0).  Stage A-h0(t+1). ----------
#pragma unroll
        for (int mf = 0; mf < 4; ++mf)
#pragma unroll
            for (int ks = 0; ks < 2; ++ks)
                fA[mf][ks] = *(const bf16x8*)(Ab + mf * 2048 + co[mf & 1][ks]);
#pragma unroll
        for (int nf = 0; nf < 2; ++nf)
#pragma unroll
            for (int ks = 0; ks < 2; ++ks)
                fB[nf][ks] = *(const bf16x8*)(Bb + nf * 2048 + co[nf & 1][ks]);
        if (t + 1 < NT) stage(A, tileM, (t + 1) * 64, nxt);
        asm volatile("s_waitcnt lgkmcnt(8)" ::: "memory");
        __builtin_amdgcn_s_barrier();
        asm volatile("s_waitcnt lgkmcnt(0)" ::: "memory");
        __builtin_amdgcn_sched_barrier(0);
        __builtin_amdgcn_s_setprio(1);
#pragma unroll
        for (int mf = 0; mf < 4; ++mf)
#pragma unroll
            for (int nf = 0; nf < 2; ++nf)
#pragma unroll
                for (int ks = 0; ks < 2; ++ks)
                    acc[mf][nf] = __builtin_amdgcn_mfma_f32_16x16x32_bf16(
                        fA[mf][ks], fB[nf][ks], acc[mf][nf], 0, 0, 0);
        __builtin_amdgcn_s_setprio(0);
        __builtin_amdgcn_s_barrier();

        // ---------- phase 2: quadrant (qm0, qn1).  Stage A-h1(t+1). ----------
#pragma unroll
        for (int nf = 0; nf < 2; ++nf)
#pragma unroll
            for (int ks = 0; ks < 2; ++ks)
                fC[nf][ks] = *(const bf16x8*)(Bb + 4096 + nf * 2048 + co[nf & 1][ks]);
        if (t + 1 < NT) stage(A, tileM + 128, (t + 1) * 64, nxt + 16384);
        __builtin_amdgcn_s_barrier();
        asm volatile("s_waitcnt lgkmcnt(0)" ::: "memory");
        __builtin_amdgcn_sched_barrier(0);
        __builtin_amdgcn_s_setprio(1);
#pragma unroll
        for (int mf = 0; mf < 4; ++mf)
#pragma unroll
            for (int nf = 0; nf < 2; ++nf)
#pragma unroll
                for (int ks = 0; ks < 2; ++ks)
                    acc[mf][2 + nf] = __builtin_amdgcn_mfma_f32_16x16x32_bf16(
                        fA[mf][ks], fC[nf][ks], acc[mf][2 + nf], 0, 0, 0);
        __builtin_amdgcn_s_setprio(0);
        __builtin_amdgcn_s_barrier();
        // all B reads of cur done -> phases 3-4 may overwrite cur.B with B(t+2)

        // ---------- phase 3: quadrant (qm1, qn1).  Stage B-h0(t+2) -> cur.B. --
#pragma unroll
        for (int mf = 0; mf < 4; ++mf)
#pragma unroll
            for (int ks = 0; ks < 2; ++ks)
                fD[mf][ks] = *(const bf16x8*)(Ab + 8192 + mf * 2048 + co[mf & 1][ks]);
        if (t + 2 < NT) stage(W, tileN, (t + 2) * 64, cur + 32768);
        __builtin_amdgcn_s_barrier();
        asm volatile("s_waitcnt lgkmcnt(0)" ::: "memory");
        __builtin_amdgcn_sched_barrier(0);
        __builtin_amdgcn_s_setprio(1);
#pragma unroll
        for (int mf = 0; mf < 4; ++mf)
#pragma unroll
            for (int nf = 0; nf < 2; ++nf)
#pragma unroll
                for (int ks = 0; ks < 2; ++ks)
                    acc[4 + mf][2 + nf] = __builtin_amdgcn_mfma_f32_16x16x32_bf16(
                        fD[mf][ks], fC[nf][ks], acc[4 + mf][2 + nf], 0, 0, 0);
        __builtin_amdgcn_s_setprio(0);
        __builtin_amdgcn_s_barrier();

        // ---------- phase 4: quadrant (qm1, qn0).  Stage B-h1(t+2) -> cur.B. --
        if (t + 2 < NT) stage(W, tileN + 128, (t + 2) * 64, cur + 49152);
        __builtin_amdgcn_s_barrier();
        __builtin_amdgcn_sched_barrier(0);
        __builtin_amdgcn_s_setprio(1);
#pragma unroll
        for (int mf = 0; mf < 4; ++mf)
#pragma unroll
            for (int nf = 0; nf < 2; ++nf)
#pragma unroll
                for (int ks = 0; ks < 2; ++ks)
                    acc[4 + mf][nf] = __builtin_amdgcn_mfma_f32_16x16x32_bf16(
                        fD[mf][ks], fB[nf][ks], acc[4 + mf][nf], 0, 0, 0);
        __builtin_amdgcn_s_setprio(0);
        // Boundary: counted.  In-flight (youngest first): B(t+2) 4, A(t+1) 4,
        // [B(t+1) 4 if not yet landed].  vmcnt(4) -> A(t+1) and B(t+1) landed,
        // B(t+2) stays in flight.
        if (t + 2 < NT) {
            asm volatile("s_waitcnt vmcnt(4)" ::: "memory");
        } else if (t + 1 < NT) {
            asm volatile("s_waitcnt vmcnt(0)" ::: "memory");
        }
        __builtin_amdgcn_s_barrier();
    }

    // ---- epilogue: acc[mi][gate][v], all in registers. ----
    // 16x16 C/D map: col = lane&15 (= hl), row = quad*4 + v.
    const int hidx = (tileN >> 2) + wn * 16 + l15;   // global h in [0,1024)
    const float bi  = bx[hidx]        + bh[hidx];
    const float bff = bx[1024 + hidx] + bh[1024 + hidx];
    const float bo  = bx[2048 + hidx] + bh[2048 + hidx];
    const float bc  = bx[3072 + hidx] + bh[3072 + hidx];

#pragma unroll
    for (int mi = 0; mi < 8; ++mi) {
#pragma unroll
        for (int v = 0; v < 4; ++v) {
            int m = wm * 128 + mi * 16 + quad * 4 + v;
            size_t goff = (size_t)(tileM + m) * 1024 + hidx;
            float gi = acc[mi][0][v] + bi;
            float gf = acc[mi][1][v] + bff;
            float go = acc[mi][2][v] + bo;
            float gc = acc[mi][3][v] + bc;
            float c1v = c1[goff];
            float ii = sigmoidf_fast(gi);
            float ff = sigmoidf_fast(gf);
            float oo = sigmoidf_fast(go);
            float cb_ = tanhf_fast(gc);
            float cc = sigmoidf_fast(ff * c1v + ii * cb_);   // reference quirk
            float hn = tanhf_fast(cc) * oo;
            out[goff] = hn;
            out[8388608 + goff] = cc;
        }
    }
}

extern "C" void kernel_launch(void* const* d_in, const int* in_sizes, int n_in,
                              void* d_out, int out_size, void* d_ws, size_t ws_size,
                              hipStream_t stream) {
    const float* x  = (const float*)d_in[0];
    const float* h  = (const float*)d_in[1];
    const float* c1 = (const float*)d_in[2];
    const float* Wx = (const float*)d_in[3];
    const float* bx = (const float*)d_in[4];
    const float* Wh = (const float*)d_in[5];
    const float* bh = (const float*)d_in[6];
    float* out = (float*)d_out;

    char* ws = (char*)d_ws;
    unsigned short* Abf = (unsigned short*)(ws);                // 33,554,432 B
    unsigned short* Wbf = (unsigned short*)(ws + 33554432);     // 16,777,216 B

    prep_cat<<<6144, 256, 0, stream>>>(x, h, Wx, Wh, Abf, Wbf);
    gemm_lstm<<<512, 512, 0, stream>>>(Abf, Wbf, bx, bh, c1, out);
}